// Round 8
// baseline (1726.307 us; speedup 1.0000x reference)
//
#include <hip/hip_runtime.h>
#include <math.h>

#define B 2
#define S 2048
#define DIM 2048
#define H 32
#define HD 64
#define NE 6144           // 3*H*HD
#define M_ROWS 4096       // B*S
#define SCALE 0.125f      // 1/sqrt(64)

typedef __attribute__((ext_vector_type(8))) __bf16 bf16x8;
typedef __attribute__((ext_vector_type(4))) __bf16 bf16x4;
typedef __attribute__((ext_vector_type(4))) float f32x4;

// ---------------------------------------------------------------------------
// Compensated-bf16 MFMA GEMM: C[m][n] = sum_k A[m][k] * Bw[n][k]  (fp32 in/out)
// A: MxK row-major, Bw: NxK row-major. Each fp32 x = hi + lo (hi = trunc bf16,
// lo = bf16(x-hi)); C ~= Ahi.Bhi + Ahi.Blo + Alo.Bhi  (lo.lo ~ 2^-17, dropped).
// 128x128 tile, BK=32, 4 waves (2x2 of 64x64), mfma_f32_16x16x32_bf16.
// Reg-staged (split forces it) + register double-buffer prefetch of the next
// K-tile so global-load latency hides under the MFMA phase (T14-lite, m249).
// ---------------------------------------------------------------------------
#define GBM 128
#define GBN 128
#define GBK 32

// hi = fp32 with low 16 mantissa bits cleared (exact bf16 truncation)
__device__ __forceinline__ float hi_part(float x) {
  return __builtin_bit_cast(float, __builtin_bit_cast(unsigned, x) & 0xFFFF0000u);
}
__device__ __forceinline__ __bf16 hi_bf16(float x) {
  return __builtin_bit_cast(
      __bf16, (unsigned short)(__builtin_bit_cast(unsigned, x) >> 16));
}

__global__ __launch_bounds__(256)
void gemm_f32_split_mfma(const float* __restrict__ A, const float* __restrict__ Bw,
                         float* __restrict__ C, int M, int N, int K) {
  __shared__ __bf16 Ahi[GBM * GBK];   // 8 KB each, linear: row*32 + k
  __shared__ __bf16 Alo[GBM * GBK];
  __shared__ __bf16 Bhi[GBM * GBK];
  __shared__ __bf16 Blo[GBM * GBK];

  const int tid  = threadIdx.x;
  const int lane = tid & 63;
  const int wave = tid >> 6;            // 0..3
  const int wr = wave >> 1, wc = wave & 1;
  const int bx = blockIdx.x, by = blockIdx.y;

  f32x4 acc[4][4];
#pragma unroll
  for (int i = 0; i < 4; ++i)
#pragma unroll
    for (int j = 0; j < 4; ++j) acc[i][j] = (f32x4){0.f, 0.f, 0.f, 0.f};

  // staging map: thread t loads rows sr+32i (i=0..3), f32 cols sc..sc+3
  const int sr = tid >> 3;              // 0..31
  const int sc = (tid & 7) * 4;         // 0,4,..,28
  const float* Ap = A  + (size_t)(by * GBM + sr) * K + sc;
  const float* Bp = Bw + (size_t)(bx * GBN + sr) * K + sc;

  const int rA = lane & 15;             // fragment row/col within 16
  const int kb = (lane >> 4) * 8;       // fragment k-elem base

  // preload K-tile 0 into registers
  f32x4 ga[4], gb[4], gan[4], gbn[4];
#pragma unroll
  for (int i = 0; i < 4; ++i) {
    ga[i] = *(const f32x4*)(Ap + (size_t)(32 * i) * K);
    gb[i] = *(const f32x4*)(Bp + (size_t)(32 * i) * K);
  }

  for (int k0 = 0; k0 < K; k0 += GBK) {
    __syncthreads();                    // previous tile's LDS readers done
#pragma unroll
    for (int i = 0; i < 4; ++i) {
      bf16x4 ah, al, bh, bl;
#pragma unroll
      for (int e = 0; e < 4; ++e) {
        const float xa = ga[i][e];
        const float xb = gb[i][e];
        ah[e] = hi_bf16(xa);
        al[e] = (__bf16)(xa - hi_part(xa));   // exact residual -> RNE bf16
        bh[e] = hi_bf16(xb);
        bl[e] = (__bf16)(xb - hi_part(xb));
      }
      const int off = (sr + 32 * i) * GBK + sc;   // bf16 elems, 8B-aligned
      *(bf16x4*)&Ahi[off] = ah;
      *(bf16x4*)&Alo[off] = al;
      *(bf16x4*)&Bhi[off] = bh;
      *(bf16x4*)&Blo[off] = bl;
    }
    // issue next tile's loads now: latency hides under barrier + MFMA phase
    const int kn = k0 + GBK;
    if (kn < K) {
#pragma unroll
      for (int i = 0; i < 4; ++i) {
        gan[i] = *(const f32x4*)(Ap + (size_t)(32 * i) * K + kn);
        gbn[i] = *(const f32x4*)(Bp + (size_t)(32 * i) * K + kn);
      }
    }
    __syncthreads();

    bf16x8 fa[4], fb[4], ft[4];
#pragma unroll
    for (int i = 0; i < 4; ++i)
      fa[i] = *(const bf16x8*)&Ahi[(wr * 64 + i * 16 + rA) * GBK + kb];
#pragma unroll
    for (int j = 0; j < 4; ++j)
      fb[j] = *(const bf16x8*)&Bhi[(wc * 64 + j * 16 + rA) * GBK + kb];
    // pass 1: hi_A * hi_B
#pragma unroll
    for (int i = 0; i < 4; ++i)
#pragma unroll
      for (int j = 0; j < 4; ++j)
        acc[i][j] = __builtin_amdgcn_mfma_f32_16x16x32_bf16(fa[i], fb[j],
                                                            acc[i][j], 0, 0, 0);
    // pass 2: hi_A * lo_B
#pragma unroll
    for (int j = 0; j < 4; ++j)
      ft[j] = *(const bf16x8*)&Blo[(wc * 64 + j * 16 + rA) * GBK + kb];
#pragma unroll
    for (int i = 0; i < 4; ++i)
#pragma unroll
      for (int j = 0; j < 4; ++j)
        acc[i][j] = __builtin_amdgcn_mfma_f32_16x16x32_bf16(fa[i], ft[j],
                                                            acc[i][j], 0, 0, 0);
    // pass 3: lo_A * hi_B
#pragma unroll
    for (int i = 0; i < 4; ++i)
      fa[i] = *(const bf16x8*)&Alo[(wr * 64 + i * 16 + rA) * GBK + kb];
#pragma unroll
    for (int i = 0; i < 4; ++i)
#pragma unroll
      for (int j = 0; j < 4; ++j)
        acc[i][j] = __builtin_amdgcn_mfma_f32_16x16x32_bf16(fa[i], fb[j],
                                                            acc[i][j], 0, 0, 0);

    // rotate prefetch buffers (dead copy on the last iteration)
#pragma unroll
    for (int i = 0; i < 4; ++i) { ga[i] = gan[i]; gb[i] = gbn[i]; }
  }

  // epilogue: C/D layout col = lane&15, row = (lane>>4)*4 + reg  [m89/m91]
  const int cn = lane & 15;
  const int r4 = (lane >> 4) * 4;
#pragma unroll
  for (int i = 0; i < 4; ++i) {
#pragma unroll
    for (int j = 0; j < 4; ++j) {
      const int col = bx * GBN + wc * 64 + j * 16 + cn;
#pragma unroll
      for (int reg = 0; reg < 4; ++reg) {
        const int row = by * GBM + wr * 64 + i * 16 + r4 + reg;
        C[(size_t)row * N + col] = acc[i][j][reg];
      }
    }
  }
}

// ---------------------------------------------------------------------------
// RoPE in-place on q and k blocks of qkv[m][6144] (fp32); one thread per pair
// ---------------------------------------------------------------------------
__global__ __launch_bounds__(256)
void rope_kernel(float* __restrict__ qkv) {
  const int idx = blockIdx.x * 256 + threadIdx.x;  // 0 .. 8388607
  const int m  = idx >> 11;       // row (b*S+s)
  const int r  = idx & 2047;
  const int qk = r >> 10;         // 0 = q, 1 = k
  const int h  = (r >> 5) & 31;
  const int j  = r & 31;          // 0..31 (half)
  const int s  = m & (S - 1);
  // inv_freq = 10000^(-j/32) = 2^(-j*log2(10000)/32)
  const float inv = exp2f(-(float)j * (13.287712379549449f / 32.0f));
  const float ang = (float)s * inv;
  float sn, cs;
  sincosf(ang, &sn, &cs);   // accurate version (large-arg reduction matters)
  float* p = qkv + (size_t)m * NE + qk * 2048 + h * HD + j;
  const float x1 = p[0], x2 = p[32];
  p[0]  = x1 * cs - x2 * sn;
  p[32] = x1 * sn + x2 * cs;
}

// ---------------------------------------------------------------------------
// Causal flash attention, fp32. One thread per query row; 64-key K/V LDS tiles.
// 128 queries / 128 threads per block; 16-key score chunks with exact
// skip-rescale (rescale only when the chunk max raises the running max).
// grid = (S/128, H, B), block = 128
// ---------------------------------------------------------------------------
#define QB 128            // queries per block == threads per block

__global__ __launch_bounds__(QB)
void attn_fp32(const float* __restrict__ qkv, float* __restrict__ attn_out) {
  const int h  = blockIdx.y;
  const int b  = blockIdx.z;
  const int q0 = blockIdx.x * QB;
  const int tid = threadIdx.x;
  const int qi = q0 + tid;       // this thread's query position

  __shared__ float Ks[64][HD];   // 16 KB
  __shared__ float Vs[64][HD];   // 16 KB

  const size_t base = (size_t)b * S;
  float qv[HD];
  {
    const float* qp = qkv + (base + qi) * NE + h * HD;   // q block at e-offset 0
#pragma unroll
    for (int i = 0; i < HD / 4; ++i)
      *(float4*)&qv[i * 4] = *(const float4*)(qp + i * 4);
  }
  float o[HD];
#pragma unroll
  for (int d = 0; d < HD; ++d) o[d] = 0.f;
  float mrow = -INFINITY, l = 0.f;

  const int ktiles = (q0 + QB) / 64;
  for (int kt = 0; kt < ktiles; ++kt) {
    const int k0 = kt * 64;
    __syncthreads();
    // stage 64x64 K and V tiles: 1024 float4 chunks by 128 threads (coalesced)
#pragma unroll
    for (int i = 0; i < 8; ++i) {
      const int f  = i * QB + tid;       // 0..1023
      const int rr = f >> 4;
      const int cc = (f & 15) * 4;
      const float* kp = qkv + (base + k0 + rr) * NE + 2048 + h * HD + cc;
      *(float4*)&Ks[rr][cc] = *(const float4*)kp;
      *(float4*)&Vs[rr][cc] = *(const float4*)(kp + 2048);
    }
    __syncthreads();
    if (qi >= k0) {
      const int kmax = min(64, qi - k0 + 1);   // causal bound within tile
      for (int c0 = 0; c0 < kmax; c0 += 16) {
        float sc[16];
#pragma unroll
        for (int u = 0; u < 16; ++u) {
          const int kk = c0 + u;
          float dot = 0.f;
#pragma unroll
          for (int d4 = 0; d4 < HD / 4; ++d4) {
            float4 kx = *(const float4*)&Ks[kk][d4 * 4];  // broadcast read
            dot = fmaf(qv[d4 * 4 + 0], kx.x, dot);
            dot = fmaf(qv[d4 * 4 + 1], kx.y, dot);
            dot = fmaf(qv[d4 * 4 + 2], kx.z, dot);
            dot = fmaf(qv[d4 * 4 + 3], kx.w, dot);
          }
          sc[u] = (kk < kmax) ? dot * SCALE : -INFINITY;
        }
        float cmax = sc[0];
#pragma unroll
        for (int u = 1; u < 16; ++u) cmax = fmaxf(cmax, sc[u]);
        if (cmax > mrow) {               // exact skip: corr==1 when not taken
          const float corr = __expf(mrow - cmax);  // exp(-inf)=0 first time
          l *= corr;
#pragma unroll
          for (int d = 0; d < HD; ++d) o[d] *= corr;
          mrow = cmax;                   // mrow stays the true running max
        }
#pragma unroll
        for (int u = 0; u < 16; ++u) {
          const float p = __expf(sc[u] - mrow);   // masked -> exp(-inf)=0
          l += p;
#pragma unroll
          for (int d4 = 0; d4 < HD / 4; ++d4) {
            float4 vx = *(const float4*)&Vs[c0 + u][d4 * 4];
            o[d4 * 4 + 0] = fmaf(p, vx.x, o[d4 * 4 + 0]);
            o[d4 * 4 + 1] = fmaf(p, vx.y, o[d4 * 4 + 1]);
            o[d4 * 4 + 2] = fmaf(p, vx.z, o[d4 * 4 + 2]);
            o[d4 * 4 + 3] = fmaf(p, vx.w, o[d4 * 4 + 3]);
          }
        }
      }
    }
  }
  const float invl = 1.f / l;
  float* op = attn_out + (base + qi) * (H * HD) + h * HD;
#pragma unroll
  for (int d4 = 0; d4 < HD / 4; ++d4) {
    float4 ov = make_float4(o[d4 * 4 + 0] * invl, o[d4 * 4 + 1] * invl,
                            o[d4 * 4 + 2] * invl, o[d4 * 4 + 3] * invl);
    *(float4*)(op + d4 * 4) = ov;
  }
}

// ---------------------------------------------------------------------------
extern "C" void kernel_launch(void* const* d_in, const int* in_sizes, int n_in,
                              void* d_out, int out_size, void* d_ws, size_t ws_size,
                              hipStream_t stream) {
  (void)in_sizes; (void)n_in; (void)out_size; (void)ws_size;
  const float* x     = (const float*)d_in[0];
  const float* w_qkv = (const float*)d_in[1];
  const float* w_o   = (const float*)d_in[2];
  float* out = (float*)d_out;

  float* qkv      = (float*)d_ws;                       // 4096*6144*4 = 100.7 MB
  float* attn_out = qkv + (size_t)M_ROWS * NE;          // 4096*2048*4 =  33.5 MB
                                                        // total 128 MiB exactly

  // 1) QKV projection (compensated bf16 MFMA): qkv = x . w_qkv^T
  gemm_f32_split_mfma<<<dim3(NE / GBN, M_ROWS / GBM), 256, 0, stream>>>(
      x, w_qkv, qkv, M_ROWS, NE, DIM);
  // 2) RoPE on q and k (in place, fp32)
  rope_kernel<<<(M_ROWS * 2048) / 256, 256, 0, stream>>>(qkv);
  // 3) causal flash attention -> attn_out[m][h*HD+d] (fp32)
  attn_fp32<<<dim3(S / QB, H, B), QB, 0, stream>>>(qkv, attn_out);
  // 4) output projection (compensated bf16 MFMA): out = attn_out . w_o^T
  gemm_f32_split_mfma<<<dim3(DIM / GBN, M_ROWS / GBM), 256, 0, stream>>>(
      attn_out, w_o, out, M_ROWS, DIM, DIM);
}